// Round 2
// baseline (425.925 us; speedup 1.0000x reference)
//
#include <hip/hip_runtime.h>

// Problem constants: B=32, V=32, H=32, CIN=256, S=256
#define NV 32
#define NH 32
#define NB 32
#define NK 256
#define NS 256

__device__ __forceinline__ void async_load16(const float* g, float* l) {
    __builtin_amdgcn_global_load_lds(
        (const __attribute__((address_space(1))) void*)g,
        (__attribute__((address_space(3))) void*)l,
        16, 0, 0);
}

// One block per (v,h) pair. 256 threads = 4 waves.
//  out[b,v,h,s] = log( sum_k exp(x[b,k]-xmax[b]) * acc[k,s] ) + xmax[b] - log(sum_k acc[k,s])
__global__ __launch_bounds__(256, 2)
void slsum_kernel(const float* __restrict__ x,
                  const float* __restrict__ acc,
                  float* __restrict__ out)
{
    __shared__ float E[NB][NK];     // exp(x - xmax), 32 KB
    __shared__ float As[32][NS];    // staged acc chunk (32 k-rows), 32 KB; reused for x staging
    __shared__ float xmaxS[NB];

    const int tid  = threadIdx.x;
    const int lane = tid & 63;
    const int wv   = tid >> 6;        // wave id 0..3
    const int vh   = blockIdx.x;      // v*32 + h

    const float* xp = x   + (size_t)vh * NK;          // + b * (NV*NH*NK)
    const float* ap = acc + (size_t)vh * (NK * NS);   // k*NS + s
    float*       op = out + (size_t)vh * NS;          // + b * (NV*NH*NS)

    float4* Asf4 = reinterpret_cast<float4*>(&As[0][0]);
    float4* Ef4  = reinterpret_cast<float4*>(&E[0][0]);

    // ---- Phase 1: stage x slice (32x256) into As, coalesced float4 ----
    #pragma unroll
    for (int i = 0; i < 8; ++i) {
        int idx = i * 256 + tid;            // float4 index 0..2047
        int b = idx >> 6, c4 = idx & 63;
        Asf4[idx] = *reinterpret_cast<const float4*>(xp + (size_t)b * (NV*NH*NK) + c4 * 4);
    }
    __syncthreads();

    // row max: 8 consecutive lanes per b-row
    {
        const int r = tid >> 3, sub = tid & 7;
        float m = -3.402823466e38f;
        #pragma unroll
        for (int j = 0; j < 8; ++j) {
            float4 f = Asf4[r * 64 + sub * 8 + j];
            m = fmaxf(m, fmaxf(fmaxf(f.x, f.y), fmaxf(f.z, f.w)));
        }
        m = fmaxf(m, __shfl_xor(m, 1));
        m = fmaxf(m, __shfl_xor(m, 2));
        m = fmaxf(m, __shfl_xor(m, 4));
        if (sub == 0) xmaxS[r] = m;
    }
    __syncthreads();

    // E = exp(x - xmax)
    #pragma unroll
    for (int i = 0; i < 8; ++i) {
        int idx = i * 256 + tid;
        int b = idx >> 6;
        const float xm = xmaxS[b];
        float4 f = Asf4[idx];
        Ef4[idx] = make_float4(__expf(f.x - xm), __expf(f.y - xm),
                               __expf(f.z - xm), __expf(f.w - xm));
    }
    // (sync happens at top of first chunk iteration)

    // ---- Phase 2: E(32x256) * A(256x256), 8b x 4s register tile per thread ----
    const int brow = wv;              // b-group: rows brow*8 .. +7
    const int scol = lane;            // s-group: cols scol*4 .. +3

    float4 accv[8];
    #pragma unroll
    for (int i = 0; i < 8; ++i) accv[i] = make_float4(0.f, 0.f, 0.f, 0.f);
    float4 asumv = make_float4(0.f, 0.f, 0.f, 0.f);

    for (int ch = 0; ch < 8; ++ch) {
        __syncthreads();    // previous chunk consumed (ch=0: phase-1 As reads / E writes done)
        // stage 32 k-rows: wave wv loads rows wv*8..wv*8+7, one full row per instr
        #pragma unroll
        for (int j = 0; j < 8; ++j) {
            const int row = wv * 8 + j;
            async_load16(ap + (size_t)(ch * 32 + row) * NS + lane * 4, &As[row][0]);
        }
        __syncthreads();    // drains vmcnt(0): chunk resident

        #pragma unroll
        for (int k4 = 0; k4 < 8; ++k4) {
            const float4 a0 = Asf4[(k4*4+0)*64 + scol];
            const float4 a1 = Asf4[(k4*4+1)*64 + scol];
            const float4 a2 = Asf4[(k4*4+2)*64 + scol];
            const float4 a3 = Asf4[(k4*4+3)*64 + scol];
            asumv.x += (a0.x + a1.x) + (a2.x + a3.x);
            asumv.y += (a0.y + a1.y) + (a2.y + a3.y);
            asumv.z += (a0.z + a1.z) + (a2.z + a3.z);
            asumv.w += (a0.w + a1.w) + (a2.w + a3.w);
            #pragma unroll
            for (int i = 0; i < 8; ++i) {
                const float4 e = Ef4[(brow*8 + i)*64 + ch*8 + k4];  // wave-broadcast read
                accv[i].x = fmaf(e.x, a0.x, fmaf(e.y, a1.x, fmaf(e.z, a2.x, fmaf(e.w, a3.x, accv[i].x))));
                accv[i].y = fmaf(e.x, a0.y, fmaf(e.y, a1.y, fmaf(e.z, a2.y, fmaf(e.w, a3.y, accv[i].y))));
                accv[i].z = fmaf(e.x, a0.z, fmaf(e.y, a1.z, fmaf(e.z, a2.z, fmaf(e.w, a3.z, accv[i].z))));
                accv[i].w = fmaf(e.x, a0.w, fmaf(e.y, a1.w, fmaf(e.z, a2.w, fmaf(e.w, a3.w, accv[i].w))));
            }
        }
    }

    // ---- Epilogue: out = log(acc) + xmax[b] - log(asum[s]) ----
    const float la0 = __logf(asumv.x);
    const float la1 = __logf(asumv.y);
    const float la2 = __logf(asumv.z);
    const float la3 = __logf(asumv.w);

    #pragma unroll
    for (int i = 0; i < 8; ++i) {
        const int b = brow * 8 + i;
        const float xm = xmaxS[b];
        float4 o;
        o.x = __logf(accv[i].x) + xm - la0;
        o.y = __logf(accv[i].y) + xm - la1;
        o.z = __logf(accv[i].z) + xm - la2;
        o.w = __logf(accv[i].w) + xm - la3;
        *reinterpret_cast<float4*>(op + (size_t)b * (NV*NH*NS) + scol * 4) = o;
    }
}

extern "C" void kernel_launch(void* const* d_in, const int* in_sizes, int n_in,
                              void* d_out, int out_size, void* d_ws, size_t ws_size,
                              hipStream_t stream) {
    const float* x   = (const float*)d_in[0];   // (B,V,H,CIN) fp32
    const float* acc = (const float*)d_in[1];   // (V,H,CIN,S) fp32
    float* out = (float*)d_out;                 // (B,V,H,S) fp32
    slsum_kernel<<<dim3(NV * NH), dim3(256), 0, stream>>>(x, acc, out);
}

// Round 5
// 391.727 us; speedup vs baseline: 1.0873x; 1.0873x over previous
//
#include <hip/hip_runtime.h>

// Problem constants: B=32, V=32, H=32, CIN=256, S=256
#define NV 32
#define NH 32
#define NB 32
#define NK 256
#define NS 256
#define CH_ROWS 16
#define NCH (NK / CH_ROWS)   // 16 chunks

__device__ __forceinline__ void async_load16(const float* g, float* l) {
    __builtin_amdgcn_global_load_lds(
        (const __attribute__((address_space(1))) void*)g,
        (__attribute__((address_space(3))) void*)l,
        16, 0, 0);
}

// One block per (v,h). 256 threads = 4 waves.
//  out[b,v,h,s] = log( sum_k exp(x[b,k]-xmax[b]) * acc[k,s] ) + xmax[b] - log(sum_k acc[k,s])
__global__ __launch_bounds__(256, 2)
void slsum_kernel(const float* __restrict__ x,
                  const float* __restrict__ acc,
                  float* __restrict__ out)
{
    __shared__ float E[NB][NK];              // exp(x - xmax); also x staging. 32 KB
    __shared__ float Abuf[2][CH_ROWS][NS];   // double-buffered acc chunks, 2 x 16 KB
    __shared__ float xmaxS[NB];

    const int tid  = threadIdx.x;
    const int lane = tid & 63;
    const int wv   = tid >> 6;        // wave id 0..3
    const int vh   = blockIdx.x;      // v*32 + h

    const float* xp = x   + (size_t)vh * NK;          // + b * (NV*NH*NK)
    const float* ap = acc + (size_t)vh * (NK * NS);   // k*NS + s
    float*       op = out + (size_t)vh * NS;          // + b * (NV*NH*NS)

    float4* Ef4 = reinterpret_cast<float4*>(&E[0][0]);

    // ---- Prologue: stage chunk 0 into buf 0 (HBM latency hides under phase 1) ----
    #pragma unroll
    for (int j = 0; j < 4; ++j) {
        const int row = wv * 4 + j;          // wave-uniform LDS base; lanes land at +lane*16
        async_load16(ap + (size_t)row * NS + lane * 4, &Abuf[0][row][0]);
    }

    // ---- Phase 1: stage x slice (32x256) into E, coalesced float4 ----
    #pragma unroll
    for (int i = 0; i < 8; ++i) {
        int idx = i * 256 + tid;             // float4 index 0..2047
        int b = idx >> 6, c4 = idx & 63;
        Ef4[idx] = *reinterpret_cast<const float4*>(xp + (size_t)b * (NV*NH*NK) + c4 * 4);
    }
    __syncthreads();

    // row max: 8 consecutive lanes per b-row
    {
        const int r = tid >> 3, sub = tid & 7;
        float m = -3.402823466e38f;
        #pragma unroll
        for (int j = 0; j < 8; ++j) {
            float4 f = Ef4[r * 64 + sub * 8 + j];
            m = fmaxf(m, fmaxf(fmaxf(f.x, f.y), fmaxf(f.z, f.w)));
        }
        m = fmaxf(m, __shfl_xor(m, 1));
        m = fmaxf(m, __shfl_xor(m, 2));
        m = fmaxf(m, __shfl_xor(m, 4));
        if (sub == 0) xmaxS[r] = m;
    }
    __syncthreads();

    // E = exp(x - xmax), in place
    #pragma unroll
    for (int i = 0; i < 8; ++i) {
        int idx = i * 256 + tid;
        int b = idx >> 6;
        const float xm = xmaxS[b];
        float4 f = Ef4[idx];
        Ef4[idx] = make_float4(__expf(f.x - xm), __expf(f.y - xm),
                               __expf(f.z - xm), __expf(f.w - xm));
    }
    // (E-ready barrier is the first loop-top barrier)

    // ---- Phase 2: E(32x256) * A(256x256), 8b x 4s register tile per thread ----
    const int brow = wv;              // b rows brow*8 .. +7
    const int scol = lane;            // s cols scol*4 .. +3

    float4 accv[8];
    #pragma unroll
    for (int i = 0; i < 8; ++i) accv[i] = make_float4(0.f, 0.f, 0.f, 0.f);
    float4 asumv = make_float4(0.f, 0.f, 0.f, 0.f);

    for (int ch = 0; ch < NCH; ++ch) {
        const int cur = ch & 1;
        // Barrier's implicit vmcnt(0) drains the stage issued LAST iteration
        // (targeting buf[cur]) — it had a full compute phase to land.
        __syncthreads();

        // Issue next chunk's stage into the other buffer; lands during compute.
        if (ch + 1 < NCH) {
            #pragma unroll
            for (int j = 0; j < 4; ++j) {
                const int row = wv * 4 + j;
                async_load16(ap + (size_t)((ch + 1) * CH_ROWS + row) * NS + lane * 4,
                             &Abuf[cur ^ 1][row][0]);
            }
        }

        const float4* buff4 = reinterpret_cast<const float4*>(&Abuf[cur][0][0]);
        #pragma unroll
        for (int k4 = 0; k4 < CH_ROWS / 4; ++k4) {
            const float4 a0 = buff4[(k4*4+0)*64 + scol];
            const float4 a1 = buff4[(k4*4+1)*64 + scol];
            const float4 a2 = buff4[(k4*4+2)*64 + scol];
            const float4 a3 = buff4[(k4*4+3)*64 + scol];
            asumv.x += (a0.x + a1.x) + (a2.x + a3.x);
            asumv.y += (a0.y + a1.y) + (a2.y + a3.y);
            asumv.z += (a0.z + a1.z) + (a2.z + a3.z);
            asumv.w += (a0.w + a1.w) + (a2.w + a3.w);
            #pragma unroll
            for (int i = 0; i < 8; ++i) {
                const float4 e = Ef4[(brow*8 + i)*64 + ch*4 + k4];  // wave-broadcast read
                accv[i].x = fmaf(e.x, a0.x, fmaf(e.y, a1.x, fmaf(e.z, a2.x, fmaf(e.w, a3.x, accv[i].x))));
                accv[i].y = fmaf(e.x, a0.y, fmaf(e.y, a1.y, fmaf(e.z, a2.y, fmaf(e.w, a3.y, accv[i].y))));
                accv[i].z = fmaf(e.x, a0.z, fmaf(e.y, a1.z, fmaf(e.z, a2.z, fmaf(e.w, a3.z, accv[i].z))));
                accv[i].w = fmaf(e.x, a0.w, fmaf(e.y, a1.w, fmaf(e.z, a2.w, fmaf(e.w, a3.w, accv[i].w))));
            }
        }
    }

    // ---- Epilogue: out = log(acc) + xmax[b] - log(asum[s]) ----
    const float la0 = __logf(asumv.x);
    const float la1 = __logf(asumv.y);
    const float la2 = __logf(asumv.z);
    const float la3 = __logf(asumv.w);

    #pragma unroll
    for (int i = 0; i < 8; ++i) {
        const int b = brow * 8 + i;
        const float xm = xmaxS[b];
        float4 o;
        o.x = __logf(accv[i].x) + xm - la0;
        o.y = __logf(accv[i].y) + xm - la1;
        o.z = __logf(accv[i].z) + xm - la2;
        o.w = __logf(accv[i].w) + xm - la3;
        *reinterpret_cast<float4*>(op + (size_t)b * (NV*NH*NS) + scol * 4) = o;
    }
}

extern "C" void kernel_launch(void* const* d_in, const int* in_sizes, int n_in,
                              void* d_out, int out_size, void* d_ws, size_t ws_size,
                              hipStream_t stream) {
    const float* x   = (const float*)d_in[0];   // (B,V,H,CIN) fp32
    const float* acc = (const float*)d_in[1];   // (V,H,CIN,S) fp32
    float* out = (float*)d_out;                 // (B,V,H,S) fp32
    slsum_kernel<<<dim3(NV * NH), dim3(256), 0, stream>>>(x, acc, out);
}